// Round 2
// baseline (770.960 us; speedup 1.0000x reference)
//
#include <hip/hip_runtime.h>

#define NPIX 704
#define NIMG 24
#define NB 4
#define NCAM 6
#define DB 59
#define CT 64

// ---------------------------------------------------------------------------
// Kernel 1: per-(b,n) matrix prep.
// mats[bn*24 + ...]: [0..8] inv(post_rots), [9..17] combine = rots@inv(intrins),
//                    [18..20] post_trans, [21..23] trans
// ---------------------------------------------------------------------------
__device__ inline void inv3(const double a[9], double o[9]) {
  double c0 = a[4]*a[8] - a[5]*a[7];
  double c1 = a[3]*a[8] - a[5]*a[6];
  double c2 = a[3]*a[7] - a[4]*a[6];
  double det = a[0]*c0 - a[1]*c1 + a[2]*c2;
  double id = 1.0 / det;
  o[0] =  c0 * id;
  o[1] = (a[2]*a[7] - a[1]*a[8]) * id;
  o[2] = (a[1]*a[5] - a[2]*a[4]) * id;
  o[3] = -c1 * id;
  o[4] = (a[0]*a[8] - a[2]*a[6]) * id;
  o[5] = (a[2]*a[3] - a[0]*a[5]) * id;
  o[6] =  c2 * id;
  o[7] = (a[1]*a[6] - a[0]*a[7]) * id;
  o[8] = (a[0]*a[4] - a[1]*a[3]) * id;
}

__global__ void prep_mats(const float* __restrict__ rots, const float* __restrict__ trans,
                          const float* __restrict__ intr, const float* __restrict__ prot,
                          const float* __restrict__ ptra, float* __restrict__ mats) {
  int bn = threadIdx.x;
  if (bn >= NIMG) return;
  double pr[9], ik[9];
  for (int i = 0; i < 9; i++) { pr[i] = prot[bn*9 + i]; ik[i] = intr[bn*9 + i]; }
  double Minv[9], Kinv[9];
  inv3(pr, Minv);
  inv3(ik, Kinv);
  float* m = mats + bn*24;
  for (int i = 0; i < 9; i++) m[i] = (float)Minv[i];
  float kf[9];
  for (int i = 0; i < 9; i++) kf[i] = (float)Kinv[i];
  {
#pragma clang fp contract(off)
    for (int i = 0; i < 3; i++)
      for (int j = 0; j < 3; j++) {
        float s = rots[bn*9 + i*3 + 0] * kf[0*3 + j];
        s = s + rots[bn*9 + i*3 + 1] * kf[1*3 + j];
        s = s + rots[bn*9 + i*3 + 2] * kf[2*3 + j];
        m[9 + i*3 + j] = s;
      }
  }
  m[18] = ptra[bn*3 + 0]; m[19] = ptra[bn*3 + 1]; m[20] = ptra[bn*3 + 2];
  m[21] = trans[bn*3 + 0]; m[22] = trans[bn*3 + 1]; m[23] = trans[bn*3 + 2];
}

// ---------------------------------------------------------------------------
// Kernel 2: feat = W_depth @ x (per image), softmax over first 59 channels,
// write depth_ws[bn*704+pix][64] (59 used) and img_ws[bn*704+pix][64].
// Tile: 64 pixels x 128 outputs (123 padded), K-chunks of 64.
// ---------------------------------------------------------------------------
__global__ __launch_bounds__(256) void gemm_softmax(const float* __restrict__ x,
    const float* __restrict__ Wd, const float* __restrict__ bd,
    float* __restrict__ depth_ws, float* __restrict__ img_ws) {
  __shared__ float smem[64*68 + 64*132];   // Xt[64][68] then Wt[64][132]; F overlays
  __shared__ float sm[64], ss[64];
  float* Xt = smem;
  float* Wt = smem + 64*68;
  int t = threadIdx.x;
  int blk = blockIdx.x;
  int bn = blk / 11, tile = blk - bn*11;
  int pixbase = tile * 64;
  const float* xim = x + (size_t)bn * 512 * NPIX + pixbase;
  int pg = t & 15, og = t >> 4;
  int p0 = pg << 2, o0 = og << 3;
  float acc[8][4];
  for (int i = 0; i < 8; i++) for (int j = 0; j < 4; j++) acc[i][j] = 0.f;

  for (int kc = 0; kc < 512; kc += 64) {
    for (int i = 0; i < 16; i++) {
      int cl = (t >> 6) + (i << 2);
      Xt[cl*68 + (t & 63)] = xim[(size_t)(kc + cl) * NPIX + (t & 63)];
    }
    for (int i = 0; i < 32; i++) {
      int idx = t + (i << 8);
      int o = idx >> 6, k = idx & 63;
      Wt[k*132 + o] = (o < 123) ? Wd[o*512 + kc + k] : 0.f;
    }
    __syncthreads();
#pragma unroll 8
    for (int k = 0; k < 64; k++) {
      const float4 a  = *(const float4*)&Xt[k*68 + p0];
      const float4 w0 = *(const float4*)&Wt[k*132 + o0];
      const float4 w1 = *(const float4*)&Wt[k*132 + o0 + 4];
      float av[4] = {a.x, a.y, a.z, a.w};
      float wv[8] = {w0.x, w0.y, w0.z, w0.w, w1.x, w1.y, w1.z, w1.w};
      for (int oi = 0; oi < 8; oi++)
        for (int pi = 0; pi < 4; pi++)
          acc[oi][pi] += wv[oi] * av[pi];
    }
    __syncthreads();
  }

  // Epilogue: feat -> F overlay (F[o][p], row stride 68)
  float* F = smem;
  for (int oi = 0; oi < 8; oi++) {
    int o = o0 + oi;
    float b = (o < 123) ? bd[o] : 0.f;
    for (int pi = 0; pi < 4; pi++) F[o*68 + p0 + pi] = acc[oi][pi] + b;
  }
  __syncthreads();

  // Softmax stats per pixel (all 4 waves compute redundantly; wave0 stores)
  {
    int pix = t & 63;
    float mmax = -3.4e38f;
    for (int d = 0; d < DB; d++) mmax = fmaxf(mmax, F[d*68 + pix]);
    float s = 0.f;
    for (int d = 0; d < DB; d++) s += expf(F[d*68 + pix] - mmax);
    if (t < 64) { sm[t] = mmax; ss[t] = s; }
  }
  __syncthreads();

  // Coalesced writes: lane = channel
  {
    int c = t & 63;
    for (int p = t >> 6; p < 64; p += 4) {
      size_t rec = (size_t)(bn*NPIX + pixbase + p) * 64;
      if (c < DB) depth_ws[rec + c] = expf(F[c*68 + p] - sm[p]) / ss[p];
      img_ws[rec + c] = F[(DB + c)*68 + p];
    }
  }
}

// ---------------------------------------------------------------------------
// Kernel 3: scatter. One wave per (bn,pixel); lane = channel for atomics,
// lane = depth-bin for geometry (broadcast via shfl).
// out[((b*64 + c)*128 + gy)*128 + gx] += depth[d] * img[c]
// ---------------------------------------------------------------------------
__global__ __launch_bounds__(256) void scatter_k(const float* __restrict__ mats,
    const float* __restrict__ depth_ws, const float* __restrict__ img_ws,
    float* __restrict__ out) {
  int wid = (blockIdx.x << 2) + (threadIdx.x >> 6);
  int lane = threadIdx.x & 63;
  int bn = wid / NPIX;
  int pix = wid - bn*NPIX;
  int b = bn / NCAM;
  int h = pix / 44, w = pix - h*44;
  const float* M = mats + bn*24;

  float img_c = img_ws[(size_t)wid*64 + lane];
  float depthv = (lane < DB) ? depth_ws[(size_t)wid*64 + lane] : 0.f;

  int code = -1;
  {
#pragma clang fp contract(off)
    // frustum point for depth-bin = lane (numpy linspace computes in f64)
    float xs = (float)((double)w * (703.0 / 43.0));
    float ys = (float)(h * 17);
    float dval = (float)(lane + 1);
    float vx = xs - M[18], vy = ys - M[19], vz = dval - M[20];
    float qx = M[0]*vx + M[1]*vy + M[2]*vz;
    float qy = M[3]*vx + M[4]*vy + M[5]*vz;
    float qz = M[6]*vx + M[7]*vy + M[8]*vz;
    float rx = qx*qz, ry = qy*qz;
    float px = M[9]*rx  + M[10]*ry + M[11]*qz + M[21];
    float py = M[12]*rx + M[13]*ry + M[14]*qz + M[22];
    float pz = M[15]*rx + M[16]*ry + M[17]*qz + M[23];
    float gx = floorf((px - (-50.8f - 0.4f)) / 0.8f);
    float gy = floorf((py - (-50.8f - 0.4f)) / 0.8f);
    float gz = floorf((pz - (0.0f - 10.0f)) / 20.0f);
    bool kept = (lane < DB) && (gx >= 0.f) && (gx < 128.f) &&
                (gy >= 0.f) && (gy < 128.f) && (gz == 0.f);
    if (kept) code = (int)gy * 128 + (int)gx;
  }

  float* outb = out + ((size_t)b*64 + lane) * 16384;
  for (int d = 0; d < DB; ++d) {
    int cd = __shfl(code, d);
    if (cd >= 0) {
      float dv = __shfl(depthv, d);
      unsafeAtomicAdd(outb + cd, dv * img_c);
    }
  }
}

// ---------------------------------------------------------------------------
extern "C" void kernel_launch(void* const* d_in, const int* in_sizes, int n_in,
                              void* d_out, int out_size, void* d_ws, size_t ws_size,
                              hipStream_t stream) {
  const float* x    = (const float*)d_in[0];
  const float* rots = (const float*)d_in[1];
  const float* trn  = (const float*)d_in[2];
  const float* intr = (const float*)d_in[3];
  const float* prot = (const float*)d_in[4];
  const float* ptra = (const float*)d_in[5];
  const float* Wd   = (const float*)d_in[6];
  const float* bd   = (const float*)d_in[7];
  float* out = (float*)d_out;
  float* ws  = (float*)d_ws;

  float* mats     = ws;                       // 576 floats
  float* depth_ws = ws + 1024;                // 24*704*64
  float* img_ws   = depth_ws + (size_t)NIMG*NPIX*64;

  (void)hipMemsetAsync(d_out, 0, (size_t)out_size * sizeof(float), stream);
  prep_mats<<<1, 32, 0, stream>>>(rots, trn, intr, prot, ptra, mats);
  gemm_softmax<<<NIMG*11, 256, 0, stream>>>(x, Wd, bd, depth_ws, img_ws);
  scatter_k<<<NIMG*NPIX/4, 256, 0, stream>>>(mats, depth_ws, img_ws, out);
}